// Round 2
// baseline (464.340 us; speedup 1.0000x reference)
//
#include <hip/hip_runtime.h>

#define D_FEAT 32
#define NPB 256            // nodes per bucket (power of 2)
#define NPB_SHIFT 8
#define KMAX 512           // max buckets supported by static LDS
#define NBLKP 256          // blocks used by hist/partition (must match!)
#define SRC_BITS 17
#define SRC_MASK 0x1FFFF

// ---------------- bucketed path ----------------

// Per-block LDS histogram over coarse buckets, by dst and by src.
// counts layout (bucket-major, for one linear scan):
//   countsD[k*NBLKP + b] for k in [0,K), then countsS at offset K*NBLKP.
__global__ __launch_bounds__(256) void hist_kernel(const int* __restrict__ src,
                                                   const int* __restrict__ dst,
                                                   int* __restrict__ counts,
                                                   int n_edges, int K) {
    __shared__ int cntD[KMAX];
    __shared__ int cntS[KMAX];
    int b = blockIdx.x;
    for (int i = threadIdx.x; i < K; i += blockDim.x) { cntD[i] = 0; cntS[i] = 0; }
    __syncthreads();
    int chunk = (n_edges + NBLKP - 1) / NBLKP;
    int base = b * chunk;
    int eend = min(base + chunk, n_edges);
    for (int e = base + (int)threadIdx.x; e < eend; e += blockDim.x) {
        int d = dst[e];
        int s = src[e];
        atomicAdd(&cntD[d >> NPB_SHIFT], 1);
        atomicAdd(&cntS[s >> NPB_SHIFT], 1);
    }
    __syncthreads();
    int S0 = K * NBLKP;
    for (int i = threadIdx.x; i < K; i += blockDim.x) {
        counts[i * NBLKP + b] = cntD[i];
        counts[S0 + i * NBLKP + b] = cntS[i];
    }
}

// Per-block sums -> bsum[block]
__global__ void scan_block_sums(const int* __restrict__ data, int* __restrict__ bsum, int n) {
    __shared__ int sdata[256];
    int i = blockIdx.x * 256 + threadIdx.x;
    sdata[threadIdx.x] = (i < n) ? data[i] : 0;
    __syncthreads();
    for (int s = 128; s > 0; s >>= 1) {
        if ((int)threadIdx.x < s) sdata[threadIdx.x] += sdata[threadIdx.x + s];
        __syncthreads();
    }
    if (threadIdx.x == 0) bsum[blockIdx.x] = sdata[0];
}

// Single-block exclusive scan of bsum (in place), chunked with carry.
__global__ void scan_partials(int* __restrict__ data, int n) {
    __shared__ int buf[1024];
    __shared__ int carry_s;
    if (threadIdx.x == 0) carry_s = 0;
    __syncthreads();
    for (int base = 0; base < n; base += 1024) {
        int idx = base + (int)threadIdx.x;
        int x = (idx < n) ? data[idx] : 0;
        buf[threadIdx.x] = x;
        __syncthreads();
        int sum = x;
        for (int off = 1; off < 1024; off <<= 1) {
            int t = ((int)threadIdx.x >= off) ? buf[threadIdx.x - off] : 0;
            __syncthreads();
            sum += t;
            buf[threadIdx.x] = sum;
            __syncthreads();
        }
        int carry = carry_s;
        if (idx < n) data[idx] = carry + sum - x;  // exclusive
        __syncthreads();
        if (threadIdx.x == 1023) carry_s = carry + buf[1023];
        __syncthreads();
    }
}

// Intra-block exclusive scan + block offset; in-place safe (reads own range first).
__global__ void scan_final(const int* __restrict__ data_in, const int* __restrict__ bsum,
                           int* __restrict__ data_out, int n) {
    __shared__ int buf[256];
    int i = blockIdx.x * 256 + threadIdx.x;
    int x = (i < n) ? data_in[i] : 0;
    buf[threadIdx.x] = x;
    __syncthreads();
    int sum = x;
    for (int off = 1; off < 256; off <<= 1) {
        int t = ((int)threadIdx.x >= off) ? buf[threadIdx.x - off] : 0;
        __syncthreads();
        sum += t;
        buf[threadIdx.x] = sum;
        __syncthreads();
    }
    int excl = bsum[blockIdx.x] + sum - x;
    if (i < n) data_out[i] = excl;
    if (i == n - 1) data_out[n] = excl + x;
}

// Route edges to dst-bucket segments (packed dst_local|src) and src keys to
// src-bucket segments. Only LDS cursor atomics; global writes are short streams.
__global__ __launch_bounds__(256) void partition_kernel(const int* __restrict__ src,
                                                        const int* __restrict__ dst,
                                                        const int* __restrict__ scanned,
                                                        int* __restrict__ routed,
                                                        int n_edges, int K) {
    __shared__ int curD[KMAX];
    __shared__ int curS[KMAX];
    int b = blockIdx.x;
    int S0 = K * NBLKP;
    for (int i = threadIdx.x; i < K; i += blockDim.x) {
        curD[i] = scanned[i * NBLKP + b];
        curS[i] = scanned[S0 + i * NBLKP + b];
    }
    __syncthreads();
    int chunk = (n_edges + NBLKP - 1) / NBLKP;
    int base = b * chunk;
    int eend = min(base + chunk, n_edges);
    for (int e = base + (int)threadIdx.x; e < eend; e += blockDim.x) {
        int d = dst[e];
        int s = src[e];
        int kD = d >> NPB_SHIFT;
        int posD = atomicAdd(&curD[kD], 1);
        routed[posD] = ((d & (NPB - 1)) << SRC_BITS) | s;
        int kS = s >> NPB_SHIFT;
        int posS = atomicAdd(&curS[kS], 1);
        routed[posS] = s;
    }
}

// Per src-bucket: LDS histogram of routed src keys -> norm (no global atomics).
__global__ __launch_bounds__(256) void count_src_norm(const int* __restrict__ routed,
                                                      const int* __restrict__ scanned,
                                                      float* __restrict__ norm,
                                                      int n_nodes, int K) {
    __shared__ int bins[NPB];
    int k = blockIdx.x;
    if ((int)threadIdx.x < NPB) bins[threadIdx.x] = 0;
    __syncthreads();
    int S0 = K * NBLKP;
    int beg = scanned[S0 + k * NBLKP];
    int end = scanned[S0 + (k + 1) * NBLKP];
    int kbase = k << NPB_SHIFT;
    for (int j = beg + (int)threadIdx.x; j < end; j += blockDim.x) {
        atomicAdd(&bins[routed[j] - kbase], 1);
    }
    __syncthreads();
    int node = kbase + (int)threadIdx.x;
    if ((int)threadIdx.x < NPB && node < n_nodes) {
        int d = bins[threadIdx.x];
        norm[node] = d > 0 ? rsqrtf((float)d) : 0.0f;
    }
}

// One block per dst-bucket: LDS f32 accumulators, coalesced 128B feat gathers,
// LDS atomic adds, single coalesced output write with post-scale.
__global__ __launch_bounds__(512) void accumulate_kernel(const float* __restrict__ feat,
                                                         const int* __restrict__ routed,
                                                         const int* __restrict__ scanned,
                                                         const float* __restrict__ norm,
                                                         float* __restrict__ out,
                                                         int n_nodes, int K) {
    __shared__ float accum[NPB * D_FEAT];  // 32 KB
    int k = blockIdx.x;
    for (int i = threadIdx.x; i < NPB * D_FEAT; i += blockDim.x) accum[i] = 0.0f;
    __syncthreads();

    int beg = scanned[k * NBLKP];
    int end = scanned[(k + 1) * NBLKP];
    int slot = (int)threadIdx.x >> 5;   // 16 edge-groups
    int lane = (int)threadIdx.x & 31;

    int j = beg + slot;
    for (; j + 16 < end; j += 32) {
        int p0 = routed[j];
        int p1 = routed[j + 16];
        int s0 = p0 & SRC_MASK, dl0 = p0 >> SRC_BITS;
        int s1 = p1 & SRC_MASK, dl1 = p1 >> SRC_BITS;
        float v0 = feat[s0 * D_FEAT + lane] * norm[s0];
        float v1 = feat[s1 * D_FEAT + lane] * norm[s1];
        atomicAdd(&accum[dl0 * D_FEAT + lane], v0);
        atomicAdd(&accum[dl1 * D_FEAT + lane], v1);
    }
    if (j < end) {
        int p = routed[j];
        int s = p & SRC_MASK, dl = p >> SRC_BITS;
        atomicAdd(&accum[dl * D_FEAT + lane], feat[s * D_FEAT + lane] * norm[s]);
    }
    __syncthreads();

    int kbase = k << NPB_SHIFT;
    for (int i = threadIdx.x; i < NPB * D_FEAT; i += blockDim.x) {
        int node = kbase + (i >> 5);
        if (node < n_nodes) out[(size_t)node * D_FEAT + (i & 31)] = accum[i] * norm[node];
    }
}

// ---------------- fallback atomic-scatter path ----------------

__global__ void deg_kernel(const int* __restrict__ src, int* __restrict__ deg, int n_edges) {
    int e = blockIdx.x * blockDim.x + threadIdx.x;
    if (e < n_edges) atomicAdd(&deg[src[e]], 1);
}

__global__ void norm_kernel(const int* __restrict__ deg, float* __restrict__ norm, int n_nodes) {
    int i = blockIdx.x * blockDim.x + threadIdx.x;
    if (i < n_nodes) {
        int d = deg[i];
        norm[i] = d > 0 ? rsqrtf((float)d) : 0.0f;
    }
}

__global__ void scatter_kernel(const float* __restrict__ feat,
                               const int* __restrict__ src,
                               const int* __restrict__ dst,
                               const float* __restrict__ norm,
                               float* __restrict__ out, int n_edges) {
    int t = blockIdx.x * blockDim.x + threadIdx.x;
    int e = t >> 5;
    int d = t & 31;
    if (e < n_edges) {
        int s  = src[e];
        int dd = dst[e];
        float v = feat[s * D_FEAT + d] * norm[s];
        atomicAdd(&out[dd * D_FEAT + d], v);
    }
}

__global__ void post_scale_kernel(float4* __restrict__ out4,
                                  const float* __restrict__ norm, int n4) {
    int t = blockIdx.x * blockDim.x + threadIdx.x;
    if (t < n4) {
        float nv = norm[t >> 3];
        float4 v = out4[t];
        v.x *= nv; v.y *= nv; v.z *= nv; v.w *= nv;
        out4[t] = v;
    }
}

// ---------------- launch ----------------

extern "C" void kernel_launch(void* const* d_in, const int* in_sizes, int n_in,
                              void* d_out, int out_size, void* d_ws, size_t ws_size,
                              hipStream_t stream) {
    const float* feat = (const float*)d_in[0];
    const int*   src  = (const int*)d_in[1];
    const int*   dst  = (const int*)d_in[2];
    float* out = (float*)d_out;

    const int n_nodes = in_sizes[0] / D_FEAT;
    const int n_edges = in_sizes[1];
    const int B = 256;

    const int K = (n_nodes + NPB - 1) >> NPB_SHIFT;
    const int cnt_n = 2 * K * NBLKP;
    const int nblk2 = (cnt_n + 255) / 256;

    auto align256 = [](size_t x) { return (x + 255) & ~(size_t)255; };
    size_t off = 0;
    size_t counts_off = off; off = align256(off + (size_t)(cnt_n + 1) * sizeof(int));
    size_t bsum_off   = off; off = align256(off + (size_t)nblk2 * sizeof(int));
    size_t norm_off   = off; off = align256(off + (size_t)n_nodes * sizeof(float));
    size_t routed_off = off; off = align256(off + (size_t)2 * n_edges * sizeof(int));
    size_t needed = off;

    bool ok = (ws_size >= needed) && (K <= KMAX) && (n_nodes <= (1 << SRC_BITS));

    if (ok) {
        int*   counts = (int*)((char*)d_ws + counts_off);
        int*   bsum   = (int*)((char*)d_ws + bsum_off);
        float* norm   = (float*)((char*)d_ws + norm_off);
        int*   routed = (int*)((char*)d_ws + routed_off);

        hist_kernel<<<NBLKP, 256, 0, stream>>>(src, dst, counts, n_edges, K);
        scan_block_sums<<<nblk2, 256, 0, stream>>>(counts, bsum, cnt_n);
        scan_partials<<<1, 1024, 0, stream>>>(bsum, nblk2);
        scan_final<<<nblk2, 256, 0, stream>>>(counts, bsum, counts, cnt_n);
        partition_kernel<<<NBLKP, 256, 0, stream>>>(src, dst, counts, routed, n_edges, K);
        count_src_norm<<<K, 256, 0, stream>>>(routed, counts, norm, n_nodes, K);
        accumulate_kernel<<<K, 512, 0, stream>>>(feat, routed, counts, norm, out, n_nodes, K);
    } else {
        // fallback: atomic-scatter path (deg | norm in ws)
        int*   deg  = (int*)d_ws;
        float* norm = (float*)((char*)d_ws + (((size_t)n_nodes * sizeof(int) + 255) & ~(size_t)255));

        hipMemsetAsync(deg, 0, (size_t)n_nodes * sizeof(int), stream);
        hipMemsetAsync(d_out, 0, (size_t)out_size * sizeof(float), stream);

        deg_kernel<<<(n_edges + B - 1) / B, B, 0, stream>>>(src, deg, n_edges);
        norm_kernel<<<(n_nodes + B - 1) / B, B, 0, stream>>>(deg, norm, n_nodes);

        long long total = (long long)n_edges * 32;
        int grid = (int)((total + B - 1) / B);
        scatter_kernel<<<grid, B, 0, stream>>>(feat, src, dst, norm, out, n_edges);

        int n4 = out_size / 4;
        post_scale_kernel<<<(n4 + B - 1) / B, B, 0, stream>>>((float4*)out, norm, n4);
    }
}

// Round 3
// 445.797 us; speedup vs baseline: 1.0416x; 1.0416x over previous
//
#include <hip/hip_runtime.h>

#define D_FEAT 32
#define NPB 64             // nodes per bucket (power of 2)
#define NPB_SHIFT 6
#define KMAX 4096          // max buckets supported by static LDS
#define NBLKP 256          // blocks used by hist/partition (must match!)
#define SRC_BITS 17
#define SRC_MASK 0x1FFFF

// ---------------- bucketed path ----------------

// Per-block LDS histogram over coarse buckets, by dst and by src.
// counts layout (bucket-major, for one linear scan):
//   countsD[k*NBLKP + b] for k in [0,K), then countsS at offset K*NBLKP.
__global__ __launch_bounds__(256) void hist_kernel(const int* __restrict__ src,
                                                   const int* __restrict__ dst,
                                                   int* __restrict__ counts,
                                                   int n_edges, int K) {
    __shared__ int cntD[KMAX];
    __shared__ int cntS[KMAX];
    int b = blockIdx.x;
    for (int i = threadIdx.x; i < K; i += blockDim.x) { cntD[i] = 0; cntS[i] = 0; }
    __syncthreads();
    int chunk = (n_edges + NBLKP - 1) / NBLKP;
    int base = b * chunk;
    int eend = min(base + chunk, n_edges);
    for (int e = base + (int)threadIdx.x; e < eend; e += blockDim.x) {
        int d = dst[e];
        int s = src[e];
        atomicAdd(&cntD[d >> NPB_SHIFT], 1);
        atomicAdd(&cntS[s >> NPB_SHIFT], 1);
    }
    __syncthreads();
    int S0 = K * NBLKP;
    for (int i = threadIdx.x; i < K; i += blockDim.x) {
        counts[i * NBLKP + b] = cntD[i];
        counts[S0 + i * NBLKP + b] = cntS[i];
    }
}

// Per-block sums -> bsum[block]
__global__ void scan_block_sums(const int* __restrict__ data, int* __restrict__ bsum, int n) {
    __shared__ int sdata[256];
    int i = blockIdx.x * 256 + threadIdx.x;
    sdata[threadIdx.x] = (i < n) ? data[i] : 0;
    __syncthreads();
    for (int s = 128; s > 0; s >>= 1) {
        if ((int)threadIdx.x < s) sdata[threadIdx.x] += sdata[threadIdx.x + s];
        __syncthreads();
    }
    if (threadIdx.x == 0) bsum[blockIdx.x] = sdata[0];
}

// Single-block exclusive scan of bsum (in place), chunked with carry.
__global__ void scan_partials(int* __restrict__ data, int n) {
    __shared__ int buf[1024];
    __shared__ int carry_s;
    if (threadIdx.x == 0) carry_s = 0;
    __syncthreads();
    for (int base = 0; base < n; base += 1024) {
        int idx = base + (int)threadIdx.x;
        int x = (idx < n) ? data[idx] : 0;
        buf[threadIdx.x] = x;
        __syncthreads();
        int sum = x;
        for (int off = 1; off < 1024; off <<= 1) {
            int t = ((int)threadIdx.x >= off) ? buf[threadIdx.x - off] : 0;
            __syncthreads();
            sum += t;
            buf[threadIdx.x] = sum;
            __syncthreads();
        }
        int carry = carry_s;
        if (idx < n) data[idx] = carry + sum - x;  // exclusive
        __syncthreads();
        if (threadIdx.x == 1023) carry_s = carry + buf[1023];
        __syncthreads();
    }
}

// Intra-block exclusive scan + block offset; in-place safe.
__global__ void scan_final(const int* __restrict__ data_in, const int* __restrict__ bsum,
                           int* __restrict__ data_out, int n) {
    __shared__ int buf[256];
    int i = blockIdx.x * 256 + threadIdx.x;
    int x = (i < n) ? data_in[i] : 0;
    buf[threadIdx.x] = x;
    __syncthreads();
    int sum = x;
    for (int off = 1; off < 256; off <<= 1) {
        int t = ((int)threadIdx.x >= off) ? buf[threadIdx.x - off] : 0;
        __syncthreads();
        sum += t;
        buf[threadIdx.x] = sum;
        __syncthreads();
    }
    int excl = bsum[blockIdx.x] + sum - x;
    if (i < n) data_out[i] = excl;
    if (i == n - 1) data_out[n] = excl + x;
}

// Route edges to dst-bucket segments (packed dst_local|src) and src keys to
// src-bucket segments. Only LDS cursor atomics.
__global__ __launch_bounds__(256) void partition_kernel(const int* __restrict__ src,
                                                        const int* __restrict__ dst,
                                                        const int* __restrict__ scanned,
                                                        int* __restrict__ routed,
                                                        int n_edges, int K) {
    __shared__ int curD[KMAX];
    __shared__ int curS[KMAX];
    int b = blockIdx.x;
    int S0 = K * NBLKP;
    for (int i = threadIdx.x; i < K; i += blockDim.x) {
        curD[i] = scanned[i * NBLKP + b];
        curS[i] = scanned[S0 + i * NBLKP + b];
    }
    __syncthreads();
    int chunk = (n_edges + NBLKP - 1) / NBLKP;
    int base = b * chunk;
    int eend = min(base + chunk, n_edges);
    for (int e = base + (int)threadIdx.x; e < eend; e += blockDim.x) {
        int d = dst[e];
        int s = src[e];
        int kD = d >> NPB_SHIFT;
        int posD = atomicAdd(&curD[kD], 1);
        routed[posD] = ((d & (NPB - 1)) << SRC_BITS) | s;
        int kS = s >> NPB_SHIFT;
        int posS = atomicAdd(&curS[kS], 1);
        routed[posS] = s;
    }
}

// Per src-bucket: LDS histogram of routed src keys -> norm.
__global__ __launch_bounds__(256) void count_src_norm(const int* __restrict__ routed,
                                                      const int* __restrict__ scanned,
                                                      float* __restrict__ norm,
                                                      int n_nodes, int K) {
    __shared__ int bins[NPB];
    int k = blockIdx.x;
    if ((int)threadIdx.x < NPB) bins[threadIdx.x] = 0;
    __syncthreads();
    int S0 = K * NBLKP;
    int beg = scanned[S0 + k * NBLKP];
    int end = scanned[S0 + (k + 1) * NBLKP];
    int kbase = k << NPB_SHIFT;
    for (int j = beg + (int)threadIdx.x; j < end; j += blockDim.x) {
        atomicAdd(&bins[routed[j] - kbase], 1);
    }
    __syncthreads();
    int node = kbase + (int)threadIdx.x;
    if ((int)threadIdx.x < NPB && node < n_nodes) {
        int d = bins[threadIdx.x];
        norm[node] = d > 0 ? rsqrtf((float)d) : 0.0f;
    }
}

// One block per dst-bucket: 8KB LDS accumulator, 8 groups of 32 lanes,
// 8-wide unrolled gather for MLP. Out written exactly once, coalesced.
__global__ __launch_bounds__(256) void accumulate_kernel(const float* __restrict__ feat,
                                                         const int* __restrict__ routed,
                                                         const int* __restrict__ scanned,
                                                         const float* __restrict__ norm,
                                                         float* __restrict__ out,
                                                         int n_nodes, int K) {
    __shared__ float accum[NPB * D_FEAT];  // 8 KB
    int k = blockIdx.x;
    for (int i = threadIdx.x; i < NPB * D_FEAT; i += blockDim.x) accum[i] = 0.0f;
    __syncthreads();

    int beg = scanned[k * NBLKP];
    int end = scanned[(k + 1) * NBLKP];
    int g    = (int)threadIdx.x >> 5;   // 8 edge-groups
    int lane = (int)threadIdx.x & 31;

    int j = beg + g;
    // 8-wide unroll: 16 independent global loads in flight per group.
    for (; j + 56 < end; j += 64) {
        int p0 = routed[j];
        int p1 = routed[j + 8];
        int p2 = routed[j + 16];
        int p3 = routed[j + 24];
        int p4 = routed[j + 32];
        int p5 = routed[j + 40];
        int p6 = routed[j + 48];
        int p7 = routed[j + 56];
        int s0 = p0 & SRC_MASK, s1 = p1 & SRC_MASK, s2 = p2 & SRC_MASK, s3 = p3 & SRC_MASK;
        int s4 = p4 & SRC_MASK, s5 = p5 & SRC_MASK, s6 = p6 & SRC_MASK, s7 = p7 & SRC_MASK;
        float v0 = feat[s0 * D_FEAT + lane] * norm[s0];
        float v1 = feat[s1 * D_FEAT + lane] * norm[s1];
        float v2 = feat[s2 * D_FEAT + lane] * norm[s2];
        float v3 = feat[s3 * D_FEAT + lane] * norm[s3];
        float v4 = feat[s4 * D_FEAT + lane] * norm[s4];
        float v5 = feat[s5 * D_FEAT + lane] * norm[s5];
        float v6 = feat[s6 * D_FEAT + lane] * norm[s6];
        float v7 = feat[s7 * D_FEAT + lane] * norm[s7];
        atomicAdd(&accum[(p0 >> SRC_BITS) * D_FEAT + lane], v0);
        atomicAdd(&accum[(p1 >> SRC_BITS) * D_FEAT + lane], v1);
        atomicAdd(&accum[(p2 >> SRC_BITS) * D_FEAT + lane], v2);
        atomicAdd(&accum[(p3 >> SRC_BITS) * D_FEAT + lane], v3);
        atomicAdd(&accum[(p4 >> SRC_BITS) * D_FEAT + lane], v4);
        atomicAdd(&accum[(p5 >> SRC_BITS) * D_FEAT + lane], v5);
        atomicAdd(&accum[(p6 >> SRC_BITS) * D_FEAT + lane], v6);
        atomicAdd(&accum[(p7 >> SRC_BITS) * D_FEAT + lane], v7);
    }
    for (; j < end; j += 8) {
        int p = routed[j];
        int s = p & SRC_MASK;
        atomicAdd(&accum[(p >> SRC_BITS) * D_FEAT + lane], feat[s * D_FEAT + lane] * norm[s]);
    }
    __syncthreads();

    int kbase = k << NPB_SHIFT;
    for (int i = threadIdx.x; i < NPB * D_FEAT; i += blockDim.x) {
        int node = kbase + (i >> 5);
        if (node < n_nodes) out[(size_t)node * D_FEAT + (i & 31)] = accum[i] * norm[node];
    }
}

// ---------------- fallback atomic-scatter path ----------------

__global__ void deg_kernel(const int* __restrict__ src, int* __restrict__ deg, int n_edges) {
    int e = blockIdx.x * blockDim.x + threadIdx.x;
    if (e < n_edges) atomicAdd(&deg[src[e]], 1);
}

__global__ void norm_kernel(const int* __restrict__ deg, float* __restrict__ norm, int n_nodes) {
    int i = blockIdx.x * blockDim.x + threadIdx.x;
    if (i < n_nodes) {
        int d = deg[i];
        norm[i] = d > 0 ? rsqrtf((float)d) : 0.0f;
    }
}

__global__ void scatter_kernel(const float* __restrict__ feat,
                               const int* __restrict__ src,
                               const int* __restrict__ dst,
                               const float* __restrict__ norm,
                               float* __restrict__ out, int n_edges) {
    int t = blockIdx.x * blockDim.x + threadIdx.x;
    int e = t >> 5;
    int d = t & 31;
    if (e < n_edges) {
        int s  = src[e];
        int dd = dst[e];
        float v = feat[s * D_FEAT + d] * norm[s];
        atomicAdd(&out[dd * D_FEAT + d], v);
    }
}

__global__ void post_scale_kernel(float4* __restrict__ out4,
                                  const float* __restrict__ norm, int n4) {
    int t = blockIdx.x * blockDim.x + threadIdx.x;
    if (t < n4) {
        float nv = norm[t >> 3];
        float4 v = out4[t];
        v.x *= nv; v.y *= nv; v.z *= nv; v.w *= nv;
        out4[t] = v;
    }
}

// ---------------- launch ----------------

extern "C" void kernel_launch(void* const* d_in, const int* in_sizes, int n_in,
                              void* d_out, int out_size, void* d_ws, size_t ws_size,
                              hipStream_t stream) {
    const float* feat = (const float*)d_in[0];
    const int*   src  = (const int*)d_in[1];
    const int*   dst  = (const int*)d_in[2];
    float* out = (float*)d_out;

    const int n_nodes = in_sizes[0] / D_FEAT;
    const int n_edges = in_sizes[1];
    const int B = 256;

    const int K = (n_nodes + NPB - 1) >> NPB_SHIFT;
    const int cnt_n = 2 * K * NBLKP;
    const int nblk2 = (cnt_n + 255) / 256;

    auto align256 = [](size_t x) { return (x + 255) & ~(size_t)255; };
    size_t off = 0;
    size_t counts_off = off; off = align256(off + (size_t)(cnt_n + 1) * sizeof(int));
    size_t bsum_off   = off; off = align256(off + (size_t)nblk2 * sizeof(int));
    size_t norm_off   = off; off = align256(off + (size_t)n_nodes * sizeof(float));
    size_t routed_off = off; off = align256(off + (size_t)2 * n_edges * sizeof(int));
    size_t needed = off;

    bool ok = (ws_size >= needed) && (K <= KMAX) && (n_nodes <= (1 << SRC_BITS));

    if (ok) {
        int*   counts = (int*)((char*)d_ws + counts_off);
        int*   bsum   = (int*)((char*)d_ws + bsum_off);
        float* norm   = (float*)((char*)d_ws + norm_off);
        int*   routed = (int*)((char*)d_ws + routed_off);

        hist_kernel<<<NBLKP, 256, 0, stream>>>(src, dst, counts, n_edges, K);
        scan_block_sums<<<nblk2, 256, 0, stream>>>(counts, bsum, cnt_n);
        scan_partials<<<1, 1024, 0, stream>>>(bsum, nblk2);
        scan_final<<<nblk2, 256, 0, stream>>>(counts, bsum, counts, cnt_n);
        partition_kernel<<<NBLKP, 256, 0, stream>>>(src, dst, counts, routed, n_edges, K);
        count_src_norm<<<K, 256, 0, stream>>>(routed, counts, norm, n_nodes, K);
        accumulate_kernel<<<K, 256, 0, stream>>>(feat, routed, counts, norm, out, n_nodes, K);
    } else {
        // fallback: atomic-scatter path (deg | norm in ws)
        int*   deg  = (int*)d_ws;
        float* norm = (float*)((char*)d_ws + (((size_t)n_nodes * sizeof(int) + 255) & ~(size_t)255));

        hipMemsetAsync(deg, 0, (size_t)n_nodes * sizeof(int), stream);
        hipMemsetAsync(d_out, 0, (size_t)out_size * sizeof(float), stream);

        deg_kernel<<<(n_edges + B - 1) / B, B, 0, stream>>>(src, deg, n_edges);
        norm_kernel<<<(n_nodes + B - 1) / B, B, 0, stream>>>(deg, norm, n_nodes);

        long long total = (long long)n_edges * 32;
        int grid = (int)((total + B - 1) / B);
        scatter_kernel<<<grid, B, 0, stream>>>(feat, src, dst, norm, out, n_edges);

        int n4 = out_size / 4;
        post_scale_kernel<<<(n4 + B - 1) / B, B, 0, stream>>>((float4*)out, norm, n4);
    }
}